// Round 11
// baseline (548.063 us; speedup 1.0000x reference)
//
#include <hip/hip_runtime.h>
#include <cstdint>
#include <cstddef>

// ---------------------------------------------------------------------------
// GSF-DTA forward: 2x GCNConv (protein), 2x GCNConv (drug), 2 seq MLPs, head.
// R11: agg gather widened to uint4 (16B/lane, 8 lanes per row, 8 edges/iter/
//      wave) — R10 showed latency-bound (VALU 55%, HBM 24%, neither pipe
//      saturated); doubling bytes-in-flight per lane attacks that.
// fp8 msg table (R9); fused protein+drug dispatches (R8); bucket CSR (R4).
// ---------------------------------------------------------------------------

#define NCB 256     // chunk blocks per graph for edge passes
#define BSH 9       // bucket shift: 512 nodes per bucket (needs n <= 131072)
#define BW  512     // 1 << BSH
#define MPP 1024    // mean partial blocks (protein)
#define MPD 512     // mean partial blocks (drug)
#define MLP_NB 64

typedef __attribute__((ext_vector_type(8))) _Float16 f16x8;
typedef __attribute__((ext_vector_type(2))) _Float16 f16x2;
typedef __attribute__((ext_vector_type(2))) float f32x2;
typedef __attribute__((ext_vector_type(4))) float f32x4;

static __device__ __forceinline__ unsigned short f2h(float f) {
    _Float16 h = (_Float16)f;
    return __builtin_bit_cast(unsigned short, h);
}
static __device__ __forceinline__ f16x2 u2h(unsigned u) {
    return __builtin_bit_cast(f16x2, u);
}

// accumulate 16 fp8 (one uint4) into 8 packed f32x2
static __device__ __forceinline__ void acc16(f32x2* a, uint4 v) {
    a[0] += __builtin_amdgcn_cvt_pk_f32_fp8((int)v.x, false);
    a[1] += __builtin_amdgcn_cvt_pk_f32_fp8((int)v.x, true);
    a[2] += __builtin_amdgcn_cvt_pk_f32_fp8((int)v.y, false);
    a[3] += __builtin_amdgcn_cvt_pk_f32_fp8((int)v.y, true);
    a[4] += __builtin_amdgcn_cvt_pk_f32_fp8((int)v.z, false);
    a[5] += __builtin_amdgcn_cvt_pk_f32_fp8((int)v.z, true);
    a[6] += __builtin_amdgcn_cvt_pk_f32_fp8((int)v.w, false);
    a[7] += __builtin_amdgcn_cvt_pk_f32_fp8((int)v.w, true);
}

// ---- CSR build bodies (bucket sort by dst) ----------------------------------
static __device__ __forceinline__ void hist_body(int blk, const int* __restrict__ dst, int E,
                                                 int chunk, int* __restrict__ bcnt) {
    __shared__ int h[256];
    const int t = threadIdx.x;
    h[t] = 0; __syncthreads();
    const int e0 = blk * chunk;
    const int e1 = min(E, e0 + chunk);
    for (int e = e0 + t; e < e1; e += 256) atomicAdd(&h[dst[e] >> BSH], 1);
    __syncthreads();
    bcnt[blk * 256 + t] = h[t];
}

static __device__ __forceinline__ void scan_body(int* __restrict__ bcnt, int* __restrict__ bbase) {
    const int t = threadIdx.x;
    int run = 0;
    for (int blk = 0; blk < NCB; ++blk) {
        int idx = blk * 256 + t;
        int v = bcnt[idx]; bcnt[idx] = run; run += v;
    }
    __shared__ int sh[256];
    sh[t] = run; __syncthreads();
    for (int off = 1; off < 256; off <<= 1) {
        int add = (t >= off) ? sh[t - off] : 0;
        __syncthreads(); sh[t] += add; __syncthreads();
    }
    bbase[t] = sh[t] - run;
    if (t == 255) bbase[256] = sh[255];
}

static __device__ __forceinline__ void place_body(int blk, const int* __restrict__ src,
                                                  const int* __restrict__ dst, int E, int chunk,
                                                  const int* __restrict__ bcnt,
                                                  const int* __restrict__ bbase,
                                                  unsigned* __restrict__ ebuf) {
    __shared__ int cur[256];
    const int t = threadIdx.x;
    cur[t] = bbase[t] + bcnt[blk * 256 + t];
    __syncthreads();
    const int e0 = blk * chunk;
    const int e1 = min(E, e0 + chunk);
    for (int e = e0 + t; e < e1; e += 256) {
        int d = dst[e];
        int b = d >> BSH;
        int pos = atomicAdd(&cur[b], 1);
        ebuf[pos] = ((unsigned)src[e] << BSH) | (unsigned)(d & (BW - 1));
    }
}

static __device__ __forceinline__ void finish_body(int b, const unsigned* __restrict__ ebuf,
                                                   const int* __restrict__ bbase, int n, int E,
                                                   int* __restrict__ rowptr,
                                                   float* __restrict__ dinv,
                                                   int* __restrict__ col) {
    __shared__ int hist[BW];
    __shared__ int cur[BW];
    __shared__ int sh[256];
    const int t = threadIdx.x;
    const int nb = b << BSH;
    const int w = min(BW, n - nb);
    const int rb = bbase[b], re = bbase[b + 1];
    hist[2 * t] = 0; hist[2 * t + 1] = 0;
    __syncthreads();
    for (int i = rb + t; i < re; i += 256) atomicAdd(&hist[ebuf[i] & (BW - 1)], 1);
    __syncthreads();
    const int a0 = hist[2 * t], a1 = hist[2 * t + 1];
    if (2 * t     < w) dinv[nb + 2 * t]     = rsqrtf((float)(a0 + 1));
    if (2 * t + 1 < w) dinv[nb + 2 * t + 1] = rsqrtf((float)(a1 + 1));
    sh[t] = a0 + a1; __syncthreads();
    for (int off = 1; off < 256; off <<= 1) {
        int add = (t >= off) ? sh[t - off] : 0;
        __syncthreads(); sh[t] += add; __syncthreads();
    }
    int base = t ? sh[t - 1] : 0;
    const int p0 = rb + base, p1 = rb + base + a0;
    if (2 * t     < w) rowptr[nb + 2 * t]     = p0;
    if (2 * t + 1 < w) rowptr[nb + 2 * t + 1] = p1;
    cur[2 * t] = p0; cur[2 * t + 1] = p1;
    __syncthreads();
    for (int i = rb + t; i < re; i += 256) {
        unsigned r = ebuf[i];
        int pos = atomicAdd(&cur[r & (BW - 1)], 1);
        col[pos] = (int)(r >> BSH);
    }
    if (b == 0 && t == 0) rowptr[n] = E;
}

__global__ __launch_bounds__(256) void csr_hist2(const int* dp, int Ep_, int chp, int* bcp,
                                                 const int* dd, int Ed_, int chd, int* bcd) {
    int b = blockIdx.x;
    if (b < NCB) hist_body(b, dp, Ep_, chp, bcp);
    else         hist_body(b - NCB, dd, Ed_, chd, bcd);
}

__global__ __launch_bounds__(256) void csr_scan2(int* bcp, int* bbp, int* bcd, int* bbd) {
    if (blockIdx.x == 0) scan_body(bcp, bbp);
    else                 scan_body(bcd, bbd);
}

__global__ __launch_bounds__(256) void csr_place2(const int* sp, const int* dp, int Ep_, int chp,
                                                  const int* bcp, const int* bbp, unsigned* ebp,
                                                  const int* sd, const int* dd, int Ed_, int chd,
                                                  const int* bcd, const int* bbd, unsigned* ebd) {
    int b = blockIdx.x;
    if (b < NCB) place_body(b, sp, dp, Ep_, chp, bcp, bbp, ebp);
    else         place_body(b - NCB, sd, dd, Ed_, chd, bcd, bbd, ebd);
}

__global__ __launch_bounds__(256) void csr_finish2(const unsigned* ebp, const int* bbp, int np_,
                                                   int Ep_, int* rpp, float* dvp, int* clp, int nbkp,
                                                   const unsigned* ebd, const int* bbd, int nd_,
                                                   int Ed_, int* rpd, float* dvd, int* cld) {
    int b = blockIdx.x;
    if (b < nbkp) finish_body(b, ebp, bbp, np_, Ep_, rpp, dvp, clp);
    else          finish_body(b - nbkp, ebd, bbd, nd_, Ed_, rpd, dvd, cld);
}

// ---- x@W via MFMA f16; out = fp8( dinv[row] * (x@W) ), rows 128B ------------
template <int K, bool IN16>
static __device__ __forceinline__ void xw_body(_Float16* __restrict__ Wt,
                                               unsigned char* __restrict__ T8, int bid,
                                               const void* __restrict__ xv,
                                               const float* __restrict__ W,
                                               const float* __restrict__ dinv,
                                               uint4* __restrict__ out8, int n) {
    constexpr int CH = K / 8;
    constexpr int KS = K / 32;
    const int tid = threadIdx.x;

    for (int i = tid; i < 128 * CH; i += 256) {
        const int col = i / CH, ch = i % CH;
        f16x8 v;
        #pragma unroll
        for (int j = 0; j < 8; ++j) v[j] = (_Float16)W[(ch * 8 + j) * 128 + col];
        *(f16x8*)&Wt[(col * CH + (ch ^ (col & (CH - 1)))) * 8] = v;
    }
    __syncthreads();

    const int wv = tid >> 6, ln = tid & 63;
    const int r0 = bid * 64 + wv * 16;
    const int row = r0 + (ln & 15);
    const int kg = (ln >> 4) * 8;

    f16x8 a[KS];
    if (row < n) {
        if constexpr (IN16) {
            const unsigned short* xr = (const unsigned short*)xv + (size_t)row * K;
            #pragma unroll
            for (int ks = 0; ks < KS; ++ks)
                a[ks] = *(const f16x8*)&xr[ks * 32 + kg];
        } else {
            const float* xr = (const float*)xv + (size_t)row * K;
            #pragma unroll
            for (int ks = 0; ks < KS; ++ks) {
                float4 u0 = *(const float4*)&xr[ks * 32 + kg];
                float4 u1 = *(const float4*)&xr[ks * 32 + kg + 4];
                f16x8 v;
                v[0] = (_Float16)u0.x; v[1] = (_Float16)u0.y;
                v[2] = (_Float16)u0.z; v[3] = (_Float16)u0.w;
                v[4] = (_Float16)u1.x; v[5] = (_Float16)u1.y;
                v[6] = (_Float16)u1.z; v[7] = (_Float16)u1.w;
                a[ks] = v;
            }
        }
    } else {
        #pragma unroll
        for (int ks = 0; ks < KS; ++ks) {
            f16x8 v;
            #pragma unroll
            for (int j = 0; j < 8; ++j) v[j] = (_Float16)0.f;
            a[ks] = v;
        }
    }

    const int rw0l = wv * 16 + (ln >> 4) * 4;   // local row of lane's 4 outputs
    float dv[4];
    #pragma unroll
    for (int r = 0; r < 4; ++r) dv[r] = (bid * 64 + rw0l + r < n) ? dinv[bid * 64 + rw0l + r] : 0.f;

    const int cl = ln & 15;
    #pragma unroll
    for (int nt = 0; nt < 8; ++nt) {
        const int col = nt * 16 + cl;
        f32x4 c = {0.f, 0.f, 0.f, 0.f};
        #pragma unroll
        for (int ks = 0; ks < KS; ++ks) {
            const int ch = ks * 4 + (ln >> 4);
            f16x8 b = *(const f16x8*)&Wt[(col * CH + (ch ^ (col & (CH - 1)))) * 8];
            c = __builtin_amdgcn_mfma_f32_16x16x32_f16(a[ks], b, c, 0, 0, 0);
        }
        #pragma unroll
        for (int r = 0; r < 4; ++r) {
            int q = __builtin_amdgcn_cvt_pk_fp8_f32(c[r] * dv[r], 0.f, 0, false);
            T8[(rw0l + r) * 128 + col] = (unsigned char)q;
        }
    }
    __syncthreads();
    // bulk store: 64 rows x 128B = 512 uint4
    for (int i = tid; i < 512; i += 256) {
        const int lr = i >> 3, ch = i & 7;
        const int rr = bid * 64 + lr;
        if (rr < n) out8[(size_t)rr * 8 + ch] = *(const uint4*)&T8[lr * 128 + ch * 16];
    }
    __syncthreads();
}

__global__ __launch_bounds__(256) void xw1_fused(const float* xp, const float* Wp,
                                                 const float* dvp, uint4* op, int np_, int nbp,
                                                 const float* xd, const float* Wd,
                                                 const float* dvd, uint4* od, int nd_) {
    __shared__ _Float16 Wt[128 * 128];
    __shared__ unsigned char T8[64 * 128];
    int b = blockIdx.x;
    if (b < nbp) xw_body<128, false>(Wt, T8, b, xp, Wp, dvp, op, np_);
    else         xw_body<64,  false>(Wt, T8, b - nbp, xd, Wd, dvd, od, nd_);
}

__global__ __launch_bounds__(256) void xw2_fused(const unsigned short* xp, const float* Wp,
                                                 const float* dvp, uint4* op, int np_, int nbp,
                                                 const unsigned short* xd, const float* Wd,
                                                 const float* dvd, uint4* od, int nd_) {
    __shared__ _Float16 Wt[128 * 128];
    __shared__ unsigned char T8[64 * 128];
    int b = blockIdx.x;
    if (b < nbp) xw_body<128, true>(Wt, T8, b, xp, Wp, dvp, op, np_);
    else         xw_body<128, true>(Wt, T8, b - nbp, xd, Wd, dvd, od, nd_);
}

// ---- aggregation: wave per node, 16B/lane gather (8 lanes per row) ----------
// tab row = 128B fp8 = 8 uint4. lane = (g = ln>>4, sub = (ln>>3)&1, c = ln&7):
// edge slot g*2+sub (8 edges/iter/wave), chunk c (features c*16..c*16+15).
static __device__ __forceinline__ void agg_body(int bid, const uint4* __restrict__ tab,
                                                const int* __restrict__ rowptr,
                                                const int* __restrict__ col,
                                                const float* __restrict__ dinv,
                                                const float* __restrict__ bias,
                                                uint4* __restrict__ out, int n) {
    const int wv = threadIdx.x >> 6, ln = threadIdx.x & 63;
    const int d = bid * 4 + wv;
    if (d >= n) return;
    const int es = ((ln >> 4) << 1) | ((ln >> 3) & 1);   // edge slot 0..7
    const int c = ln & 7;                                // 16B chunk 0..7
    const int beg = rowptr[d], end = rowptr[d + 1];

    f32x2 a[8], b[8];
    #pragma unroll
    for (int i = 0; i < 8; ++i) { a[i] = (f32x2){0.f, 0.f}; b[i] = (f32x2){0.f, 0.f}; }
    if (ln < 8) acc16(a, tab[(size_t)d * 8 + c]);        // self-loop (lanes 0-7 cover row)

    int j = beg;
    for (; j + 16 <= end; j += 16) {     // 16 edges per iteration, 2 loads in flight
        int s0 = col[j + es];
        int s1 = col[j + 8 + es];
        uint4 v0 = tab[(size_t)s0 * 8 + c];
        uint4 v1 = tab[(size_t)s1 * 8 + c];
        acc16(a, v0);
        acc16(b, v1);
    }
    for (; j < end; j += 8) {            // tail octets (predicated)
        int jj = j + es;
        int s = col[min(jj, end - 1)];
        uint4 v = tab[(size_t)s * 8 + c];
        if (jj < end) acc16(b, v);
    }
    #pragma unroll
    for (int i = 0; i < 8; ++i) a[i] += b[i];

    // merge the 8 edge slots: lanes {c, c+8, ..., c+56} hold the same features
    float r[16];
    #pragma unroll
    for (int i = 0; i < 8; ++i) { r[2 * i] = a[i][0]; r[2 * i + 1] = a[i][1]; }
    #pragma unroll
    for (int i = 0; i < 16; ++i) r[i] += __shfl_xor(r[i], 8);
    #pragma unroll
    for (int i = 0; i < 16; ++i) r[i] += __shfl_xor(r[i], 16);
    #pragma unroll
    for (int i = 0; i < 16; ++i) r[i] += __shfl_xor(r[i], 32);

    if (ln < 8) {
        const float dv = dinv[d];
        const float* bp = &bias[c * 16];
        uint4 o0, o1;
        o0.x = (unsigned)f2h(fmaxf(fmaf(dv, r[0],  bp[0]),  0.f))
             | ((unsigned)f2h(fmaxf(fmaf(dv, r[1],  bp[1]),  0.f)) << 16);
        o0.y = (unsigned)f2h(fmaxf(fmaf(dv, r[2],  bp[2]),  0.f))
             | ((unsigned)f2h(fmaxf(fmaf(dv, r[3],  bp[3]),  0.f)) << 16);
        o0.z = (unsigned)f2h(fmaxf(fmaf(dv, r[4],  bp[4]),  0.f))
             | ((unsigned)f2h(fmaxf(fmaf(dv, r[5],  bp[5]),  0.f)) << 16);
        o0.w = (unsigned)f2h(fmaxf(fmaf(dv, r[6],  bp[6]),  0.f))
             | ((unsigned)f2h(fmaxf(fmaf(dv, r[7],  bp[7]),  0.f)) << 16);
        o1.x = (unsigned)f2h(fmaxf(fmaf(dv, r[8],  bp[8]),  0.f))
             | ((unsigned)f2h(fmaxf(fmaf(dv, r[9],  bp[9]),  0.f)) << 16);
        o1.y = (unsigned)f2h(fmaxf(fmaf(dv, r[10], bp[10]), 0.f))
             | ((unsigned)f2h(fmaxf(fmaf(dv, r[11], bp[11]), 0.f)) << 16);
        o1.z = (unsigned)f2h(fmaxf(fmaf(dv, r[12], bp[12]), 0.f))
             | ((unsigned)f2h(fmaxf(fmaf(dv, r[13], bp[13]), 0.f)) << 16);
        o1.w = (unsigned)f2h(fmaxf(fmaf(dv, r[14], bp[14]), 0.f))
             | ((unsigned)f2h(fmaxf(fmaf(dv, r[15], bp[15]), 0.f)) << 16);
        out[(size_t)d * 16 + 2 * c]     = o0;
        out[(size_t)d * 16 + 2 * c + 1] = o1;
    }
}

__global__ __launch_bounds__(256) void agg_fused(const uint4* tp, const int* rpp, const int* clp,
                                                 const float* dvp, const float* bp, uint4* op,
                                                 int np_, int nwbp,
                                                 const uint4* td, const int* rpd, const int* cld,
                                                 const float* dvd, const float* bd, uint4* od,
                                                 int nd_) {
    int b = blockIdx.x;
    if (b < nwbp) agg_body(b, tp, rpp, clp, dvp, bp, op, np_);
    else          agg_body(b - nwbp, td, rpd, cld, dvd, bd, od, nd_);
}

// ---- mean over rows (f16 input) + seq MLP l1, merged ------------------------
static __device__ __forceinline__ void meanp_body(int bid, const uint4* __restrict__ h, int n,
                                                  int nblk, float* __restrict__ partial) {
    const int t = threadIdx.x;
    const int c = t & 15;
    const int rl = t >> 4;
    const int rpb = (n + nblk - 1) / nblk;
    const int r0 = bid * rpb, r1 = min(n, r0 + rpb);
    float acc[8] = {0.f, 0.f, 0.f, 0.f, 0.f, 0.f, 0.f, 0.f};
    for (int r = r0 + rl; r < r1; r += 16) {
        uint4 v = h[(size_t)r * 16 + c];
        f16x2 p;
        p = u2h(v.x); acc[0] += (float)p[0]; acc[1] += (float)p[1];
        p = u2h(v.y); acc[2] += (float)p[0]; acc[3] += (float)p[1];
        p = u2h(v.z); acc[4] += (float)p[0]; acc[5] += (float)p[1];
        p = u2h(v.w); acc[6] += (float)p[0]; acc[7] += (float)p[1];
    }
    __shared__ float sh[16][128];
    #pragma unroll
    for (int k = 0; k < 8; ++k) sh[rl][c * 8 + k] = acc[k];
    __syncthreads();
    if (t < 128) {
        float s = 0.f;
        #pragma unroll
        for (int i = 0; i < 16; ++i) s += sh[i][t];
        partial[(size_t)bid * 128 + t] = s;
    }
}

static __device__ __forceinline__ void l1_body(int bid, const float* __restrict__ in,
                                               const float* __restrict__ w1, int IN,
                                               float* __restrict__ partial) {
    const int t = threadIdx.x;
    const int f = t & 127;
    const int half = t >> 7;
    const int kpb = IN / MLP_NB;
    const int k0 = bid * kpb;
    float acc = 0.f;
    #pragma unroll 4
    for (int k = k0 + half; k < k0 + kpb; k += 2)
        acc = fmaf(in[k], w1[(size_t)k * 128 + f], acc);
    __shared__ float sh2[256];
    sh2[t] = acc; __syncthreads();
    if (half == 0) partial[bid * 128 + f] = sh2[f] + sh2[128 + f];
}

__global__ __launch_bounds__(256) void meansq_fused(const uint4* hp, int np_, float* pp,
                                                    const uint4* hd, int nd_, float* pd,
                                                    const float* inp, const float* w1p, int INp,
                                                    float* mp,
                                                    const float* ind, const float* w1d, int INd,
                                                    float* md) {
    int b = blockIdx.x;
    if      (b < MPP)                 meanp_body(b, hp, np_, MPP, pp);
    else if (b < MPP + MPD)           meanp_body(b - MPP, hd, nd_, MPD, pd);
    else if (b < MPP + MPD + MLP_NB)  l1_body(b - MPP - MPD, inp, w1p, INp, mp);
    else                              l1_body(b - MPP - MPD - MLP_NB, ind, w1d, INd, md);
}

// ---- mean finish + seq finish -----------------------------------------------
static __device__ __forceinline__ void meanf_body(const float* __restrict__ partial, int nrows,
                                                  float inv_n, float* __restrict__ out) {
    const int t = threadIdx.x;
    const int c4 = (t & 31) * 4;
    float4 acc = make_float4(0.f, 0.f, 0.f, 0.f);
    for (int r = (t >> 5); r < nrows; r += 8) {
        float4 v = *(const float4*)&partial[(size_t)r * 128 + c4];
        acc.x += v.x; acc.y += v.y; acc.z += v.z; acc.w += v.w;
    }
    __shared__ float4 sh[256];
    sh[t] = acc; __syncthreads();
    for (int off = 128; off >= 32; off >>= 1) {
        if (t < off) {
            float4 a = sh[t], o = sh[t + off];
            a.x += o.x; a.y += o.y; a.z += o.z; a.w += o.w;
            sh[t] = a;
        }
        __syncthreads();
    }
    if (t < 32) {
        float4 a = sh[t];
        a.x *= inv_n; a.y *= inv_n; a.z *= inv_n; a.w *= inv_n;
        *(float4*)&out[c4] = a;
    }
}

static __device__ __forceinline__ void seqfin_body(const float* __restrict__ partial,
                                                   const float* __restrict__ b1,
                                                   const float* __restrict__ w2,
                                                   const float* __restrict__ b2,
                                                   float* __restrict__ out) {
    const int t = threadIdx.x;          // 256; only t<128 active around syncs
    __shared__ float h[128];
    if (t < 128) {
        float s = 0.f;
        #pragma unroll 8
        for (int i = 0; i < MLP_NB; ++i) s += partial[i * 128 + t];
        h[t] = fmaxf(s + b1[t], 0.f);
    }
    __syncthreads();
    if (t < 128) {
        float acc = 0.f;
        #pragma unroll 8
        for (int k = 0; k < 128; ++k) acc = fmaf(h[k], w2[k * 128 + t], acc);
        out[t] = fmaxf(acc + b2[t], 0.f);
    }
}

__global__ __launch_bounds__(256) void finish_fused(const float* pp, float invp, float* omp,
                                                    const float* pd, float invd, float* omd,
                                                    const float* sp, const float* b1p,
                                                    const float* w2p, const float* b2p, float* osp,
                                                    const float* sd, const float* b1d,
                                                    const float* w2d, const float* b2d, float* osd) {
    const int b = blockIdx.x;
    if      (b == 0) meanf_body(pp, MPP, invp, omp);
    else if (b == 1) meanf_body(pd, MPD, invd, omd);
    else if (b == 2) seqfin_body(sp, b1p, w2p, b2p, osp);
    else             seqfin_body(sd, b1d, w2d, b2d, osd);
}

// ---- head: one block, both layers -------------------------------------------
__global__ __launch_bounds__(256) void head_one(const float* pm, const float* dm,
                                                const float* ps, const float* ds2,
                                                const float* fc1w, const float* fc1b,
                                                const float* fc2w, const float* fc2b,
                                                float* out) {
    const int t = threadIdx.x;          // 256
    __shared__ float comb[512];
    if (t < 128) {
        comb[t] = pm[t]; comb[128 + t] = dm[t];
        comb[256 + t] = ps[t]; comb[384 + t] = ds2[t];
    }
    __syncthreads();
    const int f = t & 127, half = t >> 7;
    float acc = 0.f;
    const int kb = half * 256;
    #pragma unroll 8
    for (int k = kb; k < kb + 256; ++k)
        acc = fmaf(comb[k], fc1w[(size_t)k * 128 + f], acc);
    __shared__ float hs[256];
    hs[t] = acc; __syncthreads();
    __shared__ float red[128];
    if (t < 128) {
        float h = fmaxf(hs[t] + hs[128 + t] + fc1b[t], 0.f);
        red[t] = h * fc2w[t];
    }
    __syncthreads();
    for (int off = 64; off > 0; off >>= 1) {
        if (t < off) red[t] += red[t + off];
        __syncthreads();
    }
    if (t == 0) out[0] = red[0] + fc2b[0];
}

static inline size_t align_up(size_t x, size_t a) { return (x + a - 1) / a * a; }

extern "C" void kernel_launch(void* const* d_in, const int* in_sizes, int n_in,
                              void* d_out, int out_size, void* d_ws, size_t ws_size,
                              hipStream_t stream) {
    const float* px   = (const float*)d_in[0];
    const int*   pei  = (const int*)d_in[1];
    const float* dx   = (const float*)d_in[2];
    const int*   dei  = (const int*)d_in[3];
    const float* pseq = (const float*)d_in[4];
    const float* dseq = (const float*)d_in[5];
    const float* pc1w = (const float*)d_in[6];  const float* pc1b = (const float*)d_in[7];
    const float* pc2w = (const float*)d_in[8];  const float* pc2b = (const float*)d_in[9];
    const float* dc1w = (const float*)d_in[10]; const float* dc1b = (const float*)d_in[11];
    const float* dc2w = (const float*)d_in[12]; const float* dc2b = (const float*)d_in[13];
    const float* psw1 = (const float*)d_in[14]; const float* psb1 = (const float*)d_in[15];
    const float* psw2 = (const float*)d_in[16]; const float* psb2 = (const float*)d_in[17];
    const float* dsw1 = (const float*)d_in[18]; const float* dsb1 = (const float*)d_in[19];
    const float* dsw2 = (const float*)d_in[20]; const float* dsb2 = (const float*)d_in[21];
    const float* fc1w = (const float*)d_in[22]; const float* fc1b = (const float*)d_in[23];
    const float* fc2w = (const float*)d_in[24]; const float* fc2b = (const float*)d_in[25];

    const int Np = in_sizes[0] / 128, Ep = in_sizes[1] / 2;
    const int Nd = in_sizes[2] / 64,  Ed = in_sizes[3] / 2;
    const int Psd = in_sizes[4], Dsd = in_sizes[5];

    char* w = (char*)d_ws;
    size_t off = 0;
    auto carve = [&](size_t bytes) -> void* {
        void* p = w + off;
        off = align_up(off + bytes, 256);
        return p;
    };
    unsigned char* tab_p  = (unsigned char*)carve((size_t)Np * 128);      // fp8 msg table
    unsigned short* buf_p = (unsigned short*)carve((size_t)Np * 128 * 2); // f16 hidden
    unsigned char* tab_d  = (unsigned char*)carve((size_t)Nd * 128);
    unsigned short* buf_d = (unsigned short*)carve((size_t)Nd * 128 * 2);
    int*      col_p  = (int*)carve((size_t)Ep * 4);
    unsigned* ebuf_p = (unsigned*)carve((size_t)Ep * 4);
    int*      col_d  = (int*)carve((size_t)Ed * 4);
    unsigned* ebuf_d = (unsigned*)carve((size_t)Ed * 4);
    int*   bcnt_p   = (int*)carve((size_t)NCB * 256 * 4);
    int*   bcnt_d   = (int*)carve((size_t)NCB * 256 * 4);
    int*   bbase_p  = (int*)carve(257 * 4);
    int*   bbase_d  = (int*)carve(257 * 4);
    int*   rowptr_p = (int*)carve(((size_t)Np + 1) * 4);
    int*   rowptr_d = (int*)carve(((size_t)Nd + 1) * 4);
    float* dinv_p   = (float*)carve((size_t)Np * 4);
    float* dinv_d   = (float*)carve((size_t)Nd * 4);
    float* part_p   = (float*)carve((size_t)MPP * 128 * 4);
    float* part_d   = (float*)carve((size_t)MPD * 128 * 4);
    float* mlpp_p   = (float*)carve((size_t)MLP_NB * 128 * 4);
    float* mlpp_d   = (float*)carve((size_t)MLP_NB * 128 * 4);
    float* pmean    = (float*)carve(512);
    float* dmean    = (float*)carve(512);
    float* pseqo    = (float*)carve(512);
    float* dseqo    = (float*)carve(512);
    (void)ws_size; (void)n_in; (void)out_size;

    const int* psrc = pei; const int* pdst = pei + Ep;
    const int* dsrc = dei; const int* ddst = dei + Ed;
    const int chp = (((Ep + NCB - 1) / NCB) + 255) & ~255;
    const int chd = (((Ed + NCB - 1) / NCB) + 255) & ~255;
    const int nbkp = (Np + BW - 1) >> BSH, nbkd = (Nd + BW - 1) >> BSH;
    const int nbp = (Np + 63) / 64, nbd = (Nd + 63) / 64;
    const int nwbp = (Np + 3) / 4, nwbd = (Nd + 3) / 4;

    // CSR build (both graphs per dispatch)
    csr_hist2 <<<2 * NCB, 256, 0, stream>>>(pdst, Ep, chp, bcnt_p, ddst, Ed, chd, bcnt_d);
    csr_scan2 <<<2, 256, 0, stream>>>(bcnt_p, bbase_p, bcnt_d, bbase_d);
    csr_place2<<<2 * NCB, 256, 0, stream>>>(psrc, pdst, Ep, chp, bcnt_p, bbase_p, ebuf_p,
                                            dsrc, ddst, Ed, chd, bcnt_d, bbase_d, ebuf_d);
    csr_finish2<<<nbkp + nbkd, 256, 0, stream>>>(ebuf_p, bbase_p, Np, Ep, rowptr_p, dinv_p, col_p,
                                                 nbkp, ebuf_d, bbase_d, Nd, Ed, rowptr_d, dinv_d,
                                                 col_d);

    // conv1
    xw1_fused<<<nbp + nbd, 256, 0, stream>>>(px, pc1w, dinv_p, (uint4*)tab_p, Np, nbp,
                                             dx, dc1w, dinv_d, (uint4*)tab_d, Nd);
    agg_fused<<<nwbp + nwbd, 256, 0, stream>>>((const uint4*)tab_p, rowptr_p, col_p, dinv_p, pc1b,
                                               (uint4*)buf_p, Np, nwbp,
                                               (const uint4*)tab_d, rowptr_d, col_d, dinv_d, dc1b,
                                               (uint4*)buf_d, Nd);
    // conv2
    xw2_fused<<<nbp + nbd, 256, 0, stream>>>(buf_p, pc2w, dinv_p, (uint4*)tab_p, Np, nbp,
                                             buf_d, dc2w, dinv_d, (uint4*)tab_d, Nd);
    agg_fused<<<nwbp + nwbd, 256, 0, stream>>>((const uint4*)tab_p, rowptr_p, col_p, dinv_p, pc2b,
                                               (uint4*)buf_p, Np, nwbp,
                                               (const uint4*)tab_d, rowptr_d, col_d, dinv_d, dc2b,
                                               (uint4*)buf_d, Nd);
    // means + seq MLP layer 1 (one dispatch)
    meansq_fused<<<MPP + MPD + 2 * MLP_NB, 256, 0, stream>>>(
        (const uint4*)buf_p, Np, part_p, (const uint4*)buf_d, Nd, part_d,
        pseq, psw1, Psd, mlpp_p, dseq, dsw1, Dsd, mlpp_d);
    // mean finish + seq finish (one dispatch)
    finish_fused<<<4, 256, 0, stream>>>(part_p, 1.0f / (float)Np, pmean,
                                        part_d, 1.0f / (float)Nd, dmean,
                                        mlpp_p, psb1, psw2, psb2, pseqo,
                                        mlpp_d, dsb1, dsw2, dsb2, dseqo);
    // head (single block, both layers)
    head_one<<<1, 256, 0, stream>>>(pmean, dmean, pseqo, dseqo, fc1w, fc1b, fc2w, fc2b,
                                    (float*)d_out);
}

// Round 12
// 496.306 us; speedup vs baseline: 1.1043x; 1.1043x over previous
//
#include <hip/hip_runtime.h>
#include <cstdint>
#include <cstddef>

// ---------------------------------------------------------------------------
// GSF-DTA forward: 2x GCNConv (protein), 2x GCNConv (drug), 2 seq MLPs, head.
// R12: agg reverted to R10 layout (uint2/lane, best measured: 113us) + col
//      index prefetch. CSR: hist+scan+place merged into one reservation-based
//      kernel (capacity buckets, rowptr/rend). 9 kernels + 1 memset.
// fp8 msg table (R9); fused protein+drug dispatches (R8).
// ---------------------------------------------------------------------------

#define NCB 256     // chunk blocks per graph for edge passes
#define BSH 9       // bucket shift: 512 nodes per bucket (needs n <= 131072)
#define BW  512     // 1 << BSH
#define MPP 1024    // mean partial blocks (protein)
#define MPD 512     // mean partial blocks (drug)
#define MLP_NB 64

typedef __attribute__((ext_vector_type(8))) _Float16 f16x8;
typedef __attribute__((ext_vector_type(2))) _Float16 f16x2;
typedef __attribute__((ext_vector_type(2))) float f32x2;
typedef __attribute__((ext_vector_type(4))) float f32x4;

static __device__ __forceinline__ unsigned short f2h(float f) {
    _Float16 h = (_Float16)f;
    return __builtin_bit_cast(unsigned short, h);
}
static __device__ __forceinline__ f16x2 u2h(unsigned u) {
    return __builtin_bit_cast(f16x2, u);
}

// accumulate 8 fp8 (one uint2) into 4 packed f32x2
static __device__ __forceinline__ void acc8v(f32x2* a, unsigned u0, unsigned u1) {
    a[0] += __builtin_amdgcn_cvt_pk_f32_fp8((int)u0, false);
    a[1] += __builtin_amdgcn_cvt_pk_f32_fp8((int)u0, true);
    a[2] += __builtin_amdgcn_cvt_pk_f32_fp8((int)u1, false);
    a[3] += __builtin_amdgcn_cvt_pk_f32_fp8((int)u1, true);
}

// ---- CSR build: one kernel. Per block: LDS histogram of its chunk, reserve
// per-bucket ranges via global cursor atomics, scatter into reserved ranges.
static __device__ __forceinline__ void build_body(int blk, const int* __restrict__ src,
                                                  const int* __restrict__ dst, int E, int chunk,
                                                  int* __restrict__ gcur,
                                                  unsigned* __restrict__ ebuf, int cap) {
    __shared__ int h[256];
    __shared__ int base[256];
    __shared__ int lc[256];
    const int t = threadIdx.x;
    h[t] = 0; lc[t] = 0;
    __syncthreads();
    const int e0 = blk * chunk;
    const int e1 = min(E, e0 + chunk);
    for (int e = e0 + t; e < e1; e += 256) atomicAdd(&h[dst[e] >> BSH], 1);
    __syncthreads();
    base[t] = h[t] ? atomicAdd(&gcur[t], h[t]) : 0;
    __syncthreads();
    for (int e = e0 + t; e < e1; e += 256) {
        int d = dst[e];
        int b = d >> BSH;
        int p = atomicAdd(&lc[b], 1);
        ebuf[(size_t)b * cap + base[b] + p] = ((unsigned)src[e] << BSH) | (unsigned)(d & (BW - 1));
    }
}

__global__ __launch_bounds__(256) void csr_build2(const int* sp, const int* dp, int Ep_, int chp,
                                                  int* gcp, unsigned* ebp, int capp,
                                                  const int* sd, const int* dd, int Ed_, int chd,
                                                  int* gcd, unsigned* ebd, int capd) {
    int b = blockIdx.x;
    if (b < NCB) build_body(b, sp, dp, Ep_, chp, gcp, ebp, capp);
    else         build_body(b - NCB, sd, dd, Ed_, chd, gcd, ebd, capd);
}

// one block per bucket: per-node histogram -> dinv + rowptr/rend, scatter col.
static __device__ __forceinline__ void finish_body(int b, const unsigned* __restrict__ ebuf,
                                                   const int* __restrict__ cnt, int cap, int n,
                                                   int* __restrict__ rowptr,
                                                   int* __restrict__ rend,
                                                   float* __restrict__ dinv,
                                                   int* __restrict__ col) {
    __shared__ int hist[BW];
    __shared__ int cur[BW];
    __shared__ int sh[256];
    const int t = threadIdx.x;
    const int nb = b << BSH;
    const int w = min(BW, n - nb);
    const int rb = b * cap;
    const int re = rb + cnt[b];
    hist[2 * t] = 0; hist[2 * t + 1] = 0;
    __syncthreads();
    for (int i = rb + t; i < re; i += 256) atomicAdd(&hist[ebuf[i] & (BW - 1)], 1);
    __syncthreads();
    const int a0 = hist[2 * t], a1 = hist[2 * t + 1];
    if (2 * t     < w) dinv[nb + 2 * t]     = rsqrtf((float)(a0 + 1));
    if (2 * t + 1 < w) dinv[nb + 2 * t + 1] = rsqrtf((float)(a1 + 1));
    sh[t] = a0 + a1; __syncthreads();
    for (int off = 1; off < 256; off <<= 1) {
        int add = (t >= off) ? sh[t - off] : 0;
        __syncthreads(); sh[t] += add; __syncthreads();
    }
    int base = t ? sh[t - 1] : 0;
    const int p0 = rb + base, p1 = rb + base + a0;
    if (2 * t < w) {
        rowptr[nb + 2 * t] = p0;
        rend[nb + 2 * t]   = p1;
    }
    if (2 * t + 1 < w) {
        rowptr[nb + 2 * t + 1] = p1;
        rend[nb + 2 * t + 1]   = p1 + a1;
    }
    cur[2 * t] = p0; cur[2 * t + 1] = p1;
    __syncthreads();
    for (int i = rb + t; i < re; i += 256) {
        unsigned r = ebuf[i];
        int pos = atomicAdd(&cur[r & (BW - 1)], 1);
        col[pos] = (int)(r >> BSH);
    }
}

__global__ __launch_bounds__(256) void csr_finish2(const unsigned* ebp, const int* gcp, int capp,
                                                   int np_, int* rpp, int* rep, float* dvp,
                                                   int* clp, int nbkp,
                                                   const unsigned* ebd, const int* gcd, int capd,
                                                   int nd_, int* rpd, int* red, float* dvd,
                                                   int* cld) {
    int b = blockIdx.x;
    if (b < nbkp) finish_body(b, ebp, gcp, capp, np_, rpp, rep, dvp, clp);
    else          finish_body(b - nbkp, ebd, gcd, capd, nd_, rpd, red, dvd, cld);
}

// ---- x@W via MFMA f16; out = fp8( dinv[row] * (x@W) ), rows 128B ------------
template <int K, bool IN16>
static __device__ __forceinline__ void xw_body(_Float16* __restrict__ Wt,
                                               unsigned char* __restrict__ T8, int bid,
                                               const void* __restrict__ xv,
                                               const float* __restrict__ W,
                                               const float* __restrict__ dinv,
                                               uint4* __restrict__ out8, int n) {
    constexpr int CH = K / 8;
    constexpr int KS = K / 32;
    const int tid = threadIdx.x;

    for (int i = tid; i < 128 * CH; i += 256) {
        const int col = i / CH, ch = i % CH;
        f16x8 v;
        #pragma unroll
        for (int j = 0; j < 8; ++j) v[j] = (_Float16)W[(ch * 8 + j) * 128 + col];
        *(f16x8*)&Wt[(col * CH + (ch ^ (col & (CH - 1)))) * 8] = v;
    }
    __syncthreads();

    const int wv = tid >> 6, ln = tid & 63;
    const int r0 = bid * 64 + wv * 16;
    const int row = r0 + (ln & 15);
    const int kg = (ln >> 4) * 8;

    f16x8 a[KS];
    if (row < n) {
        if constexpr (IN16) {
            const unsigned short* xr = (const unsigned short*)xv + (size_t)row * K;
            #pragma unroll
            for (int ks = 0; ks < KS; ++ks)
                a[ks] = *(const f16x8*)&xr[ks * 32 + kg];
        } else {
            const float* xr = (const float*)xv + (size_t)row * K;
            #pragma unroll
            for (int ks = 0; ks < KS; ++ks) {
                float4 u0 = *(const float4*)&xr[ks * 32 + kg];
                float4 u1 = *(const float4*)&xr[ks * 32 + kg + 4];
                f16x8 v;
                v[0] = (_Float16)u0.x; v[1] = (_Float16)u0.y;
                v[2] = (_Float16)u0.z; v[3] = (_Float16)u0.w;
                v[4] = (_Float16)u1.x; v[5] = (_Float16)u1.y;
                v[6] = (_Float16)u1.z; v[7] = (_Float16)u1.w;
                a[ks] = v;
            }
        }
    } else {
        #pragma unroll
        for (int ks = 0; ks < KS; ++ks) {
            f16x8 v;
            #pragma unroll
            for (int j = 0; j < 8; ++j) v[j] = (_Float16)0.f;
            a[ks] = v;
        }
    }

    const int rw0l = wv * 16 + (ln >> 4) * 4;   // local row of lane's 4 outputs
    float dv[4];
    #pragma unroll
    for (int r = 0; r < 4; ++r) dv[r] = (bid * 64 + rw0l + r < n) ? dinv[bid * 64 + rw0l + r] : 0.f;

    const int cl = ln & 15;
    #pragma unroll
    for (int nt = 0; nt < 8; ++nt) {
        const int col = nt * 16 + cl;
        f32x4 c = {0.f, 0.f, 0.f, 0.f};
        #pragma unroll
        for (int ks = 0; ks < KS; ++ks) {
            const int ch = ks * 4 + (ln >> 4);
            f16x8 b = *(const f16x8*)&Wt[(col * CH + (ch ^ (col & (CH - 1)))) * 8];
            c = __builtin_amdgcn_mfma_f32_16x16x32_f16(a[ks], b, c, 0, 0, 0);
        }
        #pragma unroll
        for (int r = 0; r < 4; ++r) {
            int q = __builtin_amdgcn_cvt_pk_fp8_f32(c[r] * dv[r], 0.f, 0, false);
            T8[(rw0l + r) * 128 + col] = (unsigned char)q;
        }
    }
    __syncthreads();
    // bulk store: 64 rows x 128B = 512 uint4
    for (int i = tid; i < 512; i += 256) {
        const int lr = i >> 3, ch = i & 7;
        const int rr = bid * 64 + lr;
        if (rr < n) out8[(size_t)rr * 8 + ch] = *(const uint4*)&T8[lr * 128 + ch * 16];
    }
    __syncthreads();
}

__global__ __launch_bounds__(256) void xw1_fused(const float* xp, const float* Wp,
                                                 const float* dvp, uint4* op, int np_, int nbp,
                                                 const float* xd, const float* Wd,
                                                 const float* dvd, uint4* od, int nd_) {
    __shared__ _Float16 Wt[128 * 128];
    __shared__ unsigned char T8[64 * 128];
    int b = blockIdx.x;
    if (b < nbp) xw_body<128, false>(Wt, T8, b, xp, Wp, dvp, op, np_);
    else         xw_body<64,  false>(Wt, T8, b - nbp, xd, Wd, dvd, od, nd_);
}

__global__ __launch_bounds__(256) void xw2_fused(const unsigned short* xp, const float* Wp,
                                                 const float* dvp, uint4* op, int np_, int nbp,
                                                 const unsigned short* xd, const float* Wd,
                                                 const float* dvd, uint4* od, int nd_) {
    __shared__ _Float16 Wt[128 * 128];
    __shared__ unsigned char T8[64 * 128];
    int b = blockIdx.x;
    if (b < nbp) xw_body<128, true>(Wt, T8, b, xp, Wp, dvp, op, np_);
    else         xw_body<128, true>(Wt, T8, b - nbp, xd, Wd, dvd, od, nd_);
}

// ---- aggregation: R10 layout (wave per node, uint2/lane, 8 edges/iter) ------
// + software-pipelined col index loads. tab row = 128B fp8 = 16 uint2.
static __device__ __forceinline__ void agg_body(int bid, const uint2* __restrict__ tab,
                                                const int* __restrict__ rowptr,
                                                const int* __restrict__ rend,
                                                const float* __restrict__ dinv,
                                                const int* __restrict__ col,
                                                const float* __restrict__ bias,
                                                uint4* __restrict__ out, int n) {
    const int wv = threadIdx.x >> 6, ln = threadIdx.x & 63;
    const int d = bid * 4 + wv;
    if (d >= n) return;
    const int g = ln >> 4;
    const int c = ln & 15;
    const int beg = rowptr[d], end = rend[d];

    f32x2 a[4], b[4];
    #pragma unroll
    for (int i = 0; i < 4; ++i) { a[i] = (f32x2){0.f, 0.f}; b[i] = (f32x2){0.f, 0.f}; }
    if (g == 0) {                       // self-loop term
        uint2 v = tab[(size_t)d * 16 + c];
        acc8v(a, v.x, v.y);
    }

    int j = beg;
    int s0 = 0, s1 = 0;
    if (j + 8 <= end) { s0 = col[j + g]; s1 = col[j + 4 + g]; }
    for (; j + 16 <= end; j += 8) {     // prefetch next indices while gathers fly
        uint2 v0 = tab[(size_t)s0 * 16 + c];
        uint2 v1 = tab[(size_t)s1 * 16 + c];
        s0 = col[j + 8 + g];
        s1 = col[j + 12 + g];
        acc8v(a, v0.x, v0.y);
        acc8v(b, v1.x, v1.y);
    }
    if (j + 8 <= end) {                 // consume the last prefetched pair
        uint2 v0 = tab[(size_t)s0 * 16 + c];
        uint2 v1 = tab[(size_t)s1 * 16 + c];
        acc8v(a, v0.x, v0.y);
        acc8v(b, v1.x, v1.y);
        j += 8;
    }
    for (; j < end; j += 4) {           // tail quads (predicated)
        int jj = j + g;
        int s = col[min(jj, end - 1)];
        uint2 v = tab[(size_t)s * 16 + c];
        if (jj < end) acc8v(b, v.x, v.y);
    }
    #pragma unroll
    for (int i = 0; i < 4; ++i) a[i] += b[i];

    float r[8];
    #pragma unroll
    for (int i = 0; i < 4; ++i) { r[2 * i] = a[i][0]; r[2 * i + 1] = a[i][1]; }
    #pragma unroll
    for (int i = 0; i < 8; ++i) r[i] += __shfl_xor(r[i], 16);
    #pragma unroll
    for (int i = 0; i < 8; ++i) r[i] += __shfl_xor(r[i], 32);

    if (g == 0) {
        const float dv = dinv[d];
        const float* bp = &bias[c * 8];
        uint4 o;
        o.x = (unsigned)f2h(fmaxf(fmaf(dv, r[0], bp[0]), 0.f))
            | ((unsigned)f2h(fmaxf(fmaf(dv, r[1], bp[1]), 0.f)) << 16);
        o.y = (unsigned)f2h(fmaxf(fmaf(dv, r[2], bp[2]), 0.f))
            | ((unsigned)f2h(fmaxf(fmaf(dv, r[3], bp[3]), 0.f)) << 16);
        o.z = (unsigned)f2h(fmaxf(fmaf(dv, r[4], bp[4]), 0.f))
            | ((unsigned)f2h(fmaxf(fmaf(dv, r[5], bp[5]), 0.f)) << 16);
        o.w = (unsigned)f2h(fmaxf(fmaf(dv, r[6], bp[6]), 0.f))
            | ((unsigned)f2h(fmaxf(fmaf(dv, r[7], bp[7]), 0.f)) << 16);
        out[(size_t)d * 16 + c] = o;
    }
}

__global__ __launch_bounds__(256) void agg_fused(const uint2* tp, const int* rpp, const int* rep,
                                                 const float* dvp, const int* clp, const float* bp,
                                                 uint4* op, int np_, int nwbp,
                                                 const uint2* td, const int* rpd, const int* red,
                                                 const float* dvd, const int* cld, const float* bd,
                                                 uint4* od, int nd_) {
    int b = blockIdx.x;
    if (b < nwbp) agg_body(b, tp, rpp, rep, dvp, clp, bp, op, np_);
    else          agg_body(b - nwbp, td, rpd, red, dvd, cld, bd, od, nd_);
}

// ---- mean over rows (f16 input) + seq MLP l1, merged ------------------------
static __device__ __forceinline__ void meanp_body(int bid, const uint4* __restrict__ h, int n,
                                                  int nblk, float* __restrict__ partial) {
    const int t = threadIdx.x;
    const int c = t & 15;
    const int rl = t >> 4;
    const int rpb = (n + nblk - 1) / nblk;
    const int r0 = bid * rpb, r1 = min(n, r0 + rpb);
    float acc[8] = {0.f, 0.f, 0.f, 0.f, 0.f, 0.f, 0.f, 0.f};
    for (int r = r0 + rl; r < r1; r += 16) {
        uint4 v = h[(size_t)r * 16 + c];
        f16x2 p;
        p = u2h(v.x); acc[0] += (float)p[0]; acc[1] += (float)p[1];
        p = u2h(v.y); acc[2] += (float)p[0]; acc[3] += (float)p[1];
        p = u2h(v.z); acc[4] += (float)p[0]; acc[5] += (float)p[1];
        p = u2h(v.w); acc[6] += (float)p[0]; acc[7] += (float)p[1];
    }
    __shared__ float sh[16][128];
    #pragma unroll
    for (int k = 0; k < 8; ++k) sh[rl][c * 8 + k] = acc[k];
    __syncthreads();
    if (t < 128) {
        float s = 0.f;
        #pragma unroll
        for (int i = 0; i < 16; ++i) s += sh[i][t];
        partial[(size_t)bid * 128 + t] = s;
    }
}

static __device__ __forceinline__ void l1_body(int bid, const float* __restrict__ in,
                                               const float* __restrict__ w1, int IN,
                                               float* __restrict__ partial) {
    const int t = threadIdx.x;
    const int f = t & 127;
    const int half = t >> 7;
    const int kpb = IN / MLP_NB;
    const int k0 = bid * kpb;
    float acc = 0.f;
    #pragma unroll 4
    for (int k = k0 + half; k < k0 + kpb; k += 2)
        acc = fmaf(in[k], w1[(size_t)k * 128 + f], acc);
    __shared__ float sh2[256];
    sh2[t] = acc; __syncthreads();
    if (half == 0) partial[bid * 128 + f] = sh2[f] + sh2[128 + f];
}

__global__ __launch_bounds__(256) void meansq_fused(const uint4* hp, int np_, float* pp,
                                                    const uint4* hd, int nd_, float* pd,
                                                    const float* inp, const float* w1p, int INp,
                                                    float* mp,
                                                    const float* ind, const float* w1d, int INd,
                                                    float* md) {
    int b = blockIdx.x;
    if      (b < MPP)                 meanp_body(b, hp, np_, MPP, pp);
    else if (b < MPP + MPD)           meanp_body(b - MPP, hd, nd_, MPD, pd);
    else if (b < MPP + MPD + MLP_NB)  l1_body(b - MPP - MPD, inp, w1p, INp, mp);
    else                              l1_body(b - MPP - MPD - MLP_NB, ind, w1d, INd, md);
}

// ---- mean finish + seq finish -----------------------------------------------
static __device__ __forceinline__ void meanf_body(const float* __restrict__ partial, int nrows,
                                                  float inv_n, float* __restrict__ out) {
    const int t = threadIdx.x;
    const int c4 = (t & 31) * 4;
    float4 acc = make_float4(0.f, 0.f, 0.f, 0.f);
    for (int r = (t >> 5); r < nrows; r += 8) {
        float4 v = *(const float4*)&partial[(size_t)r * 128 + c4];
        acc.x += v.x; acc.y += v.y; acc.z += v.z; acc.w += v.w;
    }
    __shared__ float4 sh[256];
    sh[t] = acc; __syncthreads();
    for (int off = 128; off >= 32; off >>= 1) {
        if (t < off) {
            float4 a = sh[t], o = sh[t + off];
            a.x += o.x; a.y += o.y; a.z += o.z; a.w += o.w;
            sh[t] = a;
        }
        __syncthreads();
    }
    if (t < 32) {
        float4 a = sh[t];
        a.x *= inv_n; a.y *= inv_n; a.z *= inv_n; a.w *= inv_n;
        *(float4*)&out[c4] = a;
    }
}

static __device__ __forceinline__ void seqfin_body(const float* __restrict__ partial,
                                                   const float* __restrict__ b1,
                                                   const float* __restrict__ w2,
                                                   const float* __restrict__ b2,
                                                   float* __restrict__ out) {
    const int t = threadIdx.x;          // 256; only t<128 active around syncs
    __shared__ float h[128];
    if (t < 128) {
        float s = 0.f;
        #pragma unroll 8
        for (int i = 0; i < MLP_NB; ++i) s += partial[i * 128 + t];
        h[t] = fmaxf(s + b1[t], 0.f);
    }
    __syncthreads();
    if (t < 128) {
        float acc = 0.f;
        #pragma unroll 8
        for (int k = 0; k < 128; ++k) acc = fmaf(h[k], w2[k * 128 + t], acc);
        out[t] = fmaxf(acc + b2[t], 0.f);
    }
}

__global__ __launch_bounds__(256) void finish_fused(const float* pp, float invp, float* omp,
                                                    const float* pd, float invd, float* omd,
                                                    const float* sp, const float* b1p,
                                                    const float* w2p, const float* b2p, float* osp,
                                                    const float* sd, const float* b1d,
                                                    const float* w2d, const float* b2d, float* osd) {
    const int b = blockIdx.x;
    if      (b == 0) meanf_body(pp, MPP, invp, omp);
    else if (b == 1) meanf_body(pd, MPD, invd, omd);
    else if (b == 2) seqfin_body(sp, b1p, w2p, b2p, osp);
    else             seqfin_body(sd, b1d, w2d, b2d, osd);
}

// ---- head: one block, both layers -------------------------------------------
__global__ __launch_bounds__(256) void head_one(const float* pm, const float* dm,
                                                const float* ps, const float* ds2,
                                                const float* fc1w, const float* fc1b,
                                                const float* fc2w, const float* fc2b,
                                                float* out) {
    const int t = threadIdx.x;          // 256
    __shared__ float comb[512];
    if (t < 128) {
        comb[t] = pm[t]; comb[128 + t] = dm[t];
        comb[256 + t] = ps[t]; comb[384 + t] = ds2[t];
    }
    __syncthreads();
    const int f = t & 127, half = t >> 7;
    float acc = 0.f;
    const int kb = half * 256;
    #pragma unroll 8
    for (int k = kb; k < kb + 256; ++k)
        acc = fmaf(comb[k], fc1w[(size_t)k * 128 + f], acc);
    __shared__ float hs[256];
    hs[t] = acc; __syncthreads();
    __shared__ float red[128];
    if (t < 128) {
        float h = fmaxf(hs[t] + hs[128 + t] + fc1b[t], 0.f);
        red[t] = h * fc2w[t];
    }
    __syncthreads();
    for (int off = 64; off > 0; off >>= 1) {
        if (t < off) red[t] += red[t + off];
        __syncthreads();
    }
    if (t == 0) out[0] = red[0] + fc2b[0];
}

static inline size_t align_up(size_t x, size_t a) { return (x + a - 1) / a * a; }

extern "C" void kernel_launch(void* const* d_in, const int* in_sizes, int n_in,
                              void* d_out, int out_size, void* d_ws, size_t ws_size,
                              hipStream_t stream) {
    const float* px   = (const float*)d_in[0];
    const int*   pei  = (const int*)d_in[1];
    const float* dx   = (const float*)d_in[2];
    const int*   dei  = (const int*)d_in[3];
    const float* pseq = (const float*)d_in[4];
    const float* dseq = (const float*)d_in[5];
    const float* pc1w = (const float*)d_in[6];  const float* pc1b = (const float*)d_in[7];
    const float* pc2w = (const float*)d_in[8];  const float* pc2b = (const float*)d_in[9];
    const float* dc1w = (const float*)d_in[10]; const float* dc1b = (const float*)d_in[11];
    const float* dc2w = (const float*)d_in[12]; const float* dc2b = (const float*)d_in[13];
    const float* psw1 = (const float*)d_in[14]; const float* psb1 = (const float*)d_in[15];
    const float* psw2 = (const float*)d_in[16]; const float* psb2 = (const float*)d_in[17];
    const float* dsw1 = (const float*)d_in[18]; const float* dsb1 = (const float*)d_in[19];
    const float* dsw2 = (const float*)d_in[20]; const float* dsb2 = (const float*)d_in[21];
    const float* fc1w = (const float*)d_in[22]; const float* fc1b = (const float*)d_in[23];
    const float* fc2w = (const float*)d_in[24]; const float* fc2b = (const float*)d_in[25];

    const int Np = in_sizes[0] / 128, Ep = in_sizes[1] / 2;
    const int Nd = in_sizes[2] / 64,  Ed = in_sizes[3] / 2;
    const int Psd = in_sizes[4], Dsd = in_sizes[5];

    // bucket capacities (binomial mean E/256, std ~sqrt(E/256); huge slack)
    const int capP = (Ep / 256 + Ep / 2048 + 1024 + 63) & ~63;
    const int capD = (Ed / 256 + Ed / 2048 + 1024 + 63) & ~63;

    char* w = (char*)d_ws;
    size_t off = 0;
    auto carve = [&](size_t bytes) -> void* {
        void* p = w + off;
        off = align_up(off + bytes, 256);
        return p;
    };
    unsigned char* tab_p  = (unsigned char*)carve((size_t)Np * 128);      // fp8 msg table
    unsigned short* buf_p = (unsigned short*)carve((size_t)Np * 128 * 2); // f16 hidden
    unsigned char* tab_d  = (unsigned char*)carve((size_t)Nd * 128);
    unsigned short* buf_d = (unsigned short*)carve((size_t)Nd * 128 * 2);
    int*      col_p  = (int*)carve((size_t)256 * capP * 4);
    unsigned* ebuf_p = (unsigned*)carve((size_t)256 * capP * 4);
    int*      col_d  = (int*)carve((size_t)256 * capD * 4);
    unsigned* ebuf_d = (unsigned*)carve((size_t)256 * capD * 4);
    int*   gcur_p   = (int*)carve(256 * 4);
    int*   gcur_d   = (int*)carve(256 * 4);
    int*   rowptr_p = (int*)carve((size_t)Np * 4);
    int*   rend_p   = (int*)carve((size_t)Np * 4);
    int*   rowptr_d = (int*)carve((size_t)Nd * 4);
    int*   rend_d   = (int*)carve((size_t)Nd * 4);
    float* dinv_p   = (float*)carve((size_t)Np * 4);
    float* dinv_d   = (float*)carve((size_t)Nd * 4);
    float* part_p   = (float*)carve((size_t)MPP * 128 * 4);
    float* part_d   = (float*)carve((size_t)MPD * 128 * 4);
    float* mlpp_p   = (float*)carve((size_t)MLP_NB * 128 * 4);
    float* mlpp_d   = (float*)carve((size_t)MLP_NB * 128 * 4);
    float* pmean    = (float*)carve(512);
    float* dmean    = (float*)carve(512);
    float* pseqo    = (float*)carve(512);
    float* dseqo    = (float*)carve(512);
    (void)ws_size; (void)n_in; (void)out_size;

    const int* psrc = pei; const int* pdst = pei + Ep;
    const int* dsrc = dei; const int* ddst = dei + Ed;
    const int chp = (((Ep + NCB - 1) / NCB) + 255) & ~255;
    const int chd = (((Ed + NCB - 1) / NCB) + 255) & ~255;
    const int nbkp = (Np + BW - 1) >> BSH, nbkd = (Nd + BW - 1) >> BSH;
    const int nbp = (Np + 63) / 64, nbd = (Nd + 63) / 64;
    const int nwbp = (Np + 3) / 4, nwbd = (Nd + 3) / 4;

    // CSR build (hist+reserve+place fused; gcur_p/gcur_d adjacent -> one memset)
    hipMemsetAsync(gcur_p, 0, 512 * 4, stream);
    csr_build2<<<2 * NCB, 256, 0, stream>>>(psrc, pdst, Ep, chp, gcur_p, ebuf_p, capP,
                                            dsrc, ddst, Ed, chd, gcur_d, ebuf_d, capD);
    csr_finish2<<<nbkp + nbkd, 256, 0, stream>>>(ebuf_p, gcur_p, capP, Np, rowptr_p, rend_p,
                                                 dinv_p, col_p, nbkp,
                                                 ebuf_d, gcur_d, capD, Nd, rowptr_d, rend_d,
                                                 dinv_d, col_d);

    // conv1
    xw1_fused<<<nbp + nbd, 256, 0, stream>>>(px, pc1w, dinv_p, (uint4*)tab_p, Np, nbp,
                                             dx, dc1w, dinv_d, (uint4*)tab_d, Nd);
    agg_fused<<<nwbp + nwbd, 256, 0, stream>>>((const uint2*)tab_p, rowptr_p, rend_p, dinv_p,
                                               col_p, pc1b, (uint4*)buf_p, Np, nwbp,
                                               (const uint2*)tab_d, rowptr_d, rend_d, dinv_d,
                                               col_d, dc1b, (uint4*)buf_d, Nd);
    // conv2
    xw2_fused<<<nbp + nbd, 256, 0, stream>>>(buf_p, pc2w, dinv_p, (uint4*)tab_p, Np, nbp,
                                             buf_d, dc2w, dinv_d, (uint4*)tab_d, Nd);
    agg_fused<<<nwbp + nwbd, 256, 0, stream>>>((const uint2*)tab_p, rowptr_p, rend_p, dinv_p,
                                               col_p, pc2b, (uint4*)buf_p, Np, nwbp,
                                               (const uint2*)tab_d, rowptr_d, rend_d, dinv_d,
                                               col_d, dc2b, (uint4*)buf_d, Nd);
    // means + seq MLP layer 1 (one dispatch)
    meansq_fused<<<MPP + MPD + 2 * MLP_NB, 256, 0, stream>>>(
        (const uint4*)buf_p, Np, part_p, (const uint4*)buf_d, Nd, part_d,
        pseq, psw1, Psd, mlpp_p, dseq, dsw1, Dsd, mlpp_d);
    // mean finish + seq finish (one dispatch)
    finish_fused<<<4, 256, 0, stream>>>(part_p, 1.0f / (float)Np, pmean,
                                        part_d, 1.0f / (float)Nd, dmean,
                                        mlpp_p, psb1, psw2, psb2, pseqo,
                                        mlpp_d, dsb1, dsw2, dsb2, dseqo);
    // head (single block, both layers)
    head_one<<<1, 256, 0, stream>>>(pmean, dmean, pseqo, dseqo, fc1w, fc1b, fc2w, fc2b,
                                    (float*)d_out);
}

// Round 13
// 494.654 us; speedup vs baseline: 1.1080x; 1.0033x over previous
//
#include <hip/hip_runtime.h>
#include <cstdint>
#include <cstddef>

// ---------------------------------------------------------------------------
// GSF-DTA forward: 2x GCNConv (protein), 2x GCNConv (drug), 2 seq MLPs, head.
// R13: agg gathers via 32-bit byte offsets (SGPR base + VGPR voffset; tables
//      <=12.8MB) — cuts the 64-bit per-lane address chains that dominated
//      VALU (67% busy vs ~6% useful-unpack arithmetic).
// R12 reservation CSR; fp8 msg table (R9); fused dispatches (R8).
// ---------------------------------------------------------------------------

#define NCB 256     // chunk blocks per graph for edge passes
#define BSH 9       // bucket shift: 512 nodes per bucket (needs n <= 131072)
#define BW  512     // 1 << BSH
#define MPP 1024    // mean partial blocks (protein)
#define MPD 512     // mean partial blocks (drug)
#define MLP_NB 64

typedef __attribute__((ext_vector_type(8))) _Float16 f16x8;
typedef __attribute__((ext_vector_type(2))) _Float16 f16x2;
typedef __attribute__((ext_vector_type(2))) float f32x2;
typedef __attribute__((ext_vector_type(4))) float f32x4;

static __device__ __forceinline__ unsigned short f2h(float f) {
    _Float16 h = (_Float16)f;
    return __builtin_bit_cast(unsigned short, h);
}
static __device__ __forceinline__ f16x2 u2h(unsigned u) {
    return __builtin_bit_cast(f16x2, u);
}

// accumulate 8 fp8 (one uint2) into 4 packed f32x2
static __device__ __forceinline__ void acc8v(f32x2* a, unsigned u0, unsigned u1) {
    a[0] += __builtin_amdgcn_cvt_pk_f32_fp8((int)u0, false);
    a[1] += __builtin_amdgcn_cvt_pk_f32_fp8((int)u0, true);
    a[2] += __builtin_amdgcn_cvt_pk_f32_fp8((int)u1, false);
    a[3] += __builtin_amdgcn_cvt_pk_f32_fp8((int)u1, true);
}

// ---- CSR build: one kernel. Per block: LDS histogram of its chunk, reserve
// per-bucket ranges via global cursor atomics, scatter into reserved ranges.
static __device__ __forceinline__ void build_body(int blk, const int* __restrict__ src,
                                                  const int* __restrict__ dst, int E, int chunk,
                                                  int* __restrict__ gcur,
                                                  unsigned* __restrict__ ebuf, int cap) {
    __shared__ int h[256];
    __shared__ int base[256];
    __shared__ int lc[256];
    const int t = threadIdx.x;
    h[t] = 0; lc[t] = 0;
    __syncthreads();
    const int e0 = blk * chunk;
    const int e1 = min(E, e0 + chunk);
    for (int e = e0 + t; e < e1; e += 256) atomicAdd(&h[dst[e] >> BSH], 1);
    __syncthreads();
    base[t] = h[t] ? atomicAdd(&gcur[t], h[t]) : 0;
    __syncthreads();
    for (int e = e0 + t; e < e1; e += 256) {
        int d = dst[e];
        int b = d >> BSH;
        int p = atomicAdd(&lc[b], 1);
        ebuf[(size_t)b * cap + base[b] + p] = ((unsigned)src[e] << BSH) | (unsigned)(d & (BW - 1));
    }
}

__global__ __launch_bounds__(256) void csr_build2(const int* sp, const int* dp, int Ep_, int chp,
                                                  int* gcp, unsigned* ebp, int capp,
                                                  const int* sd, const int* dd, int Ed_, int chd,
                                                  int* gcd, unsigned* ebd, int capd) {
    int b = blockIdx.x;
    if (b < NCB) build_body(b, sp, dp, Ep_, chp, gcp, ebp, capp);
    else         build_body(b - NCB, sd, dd, Ed_, chd, gcd, ebd, capd);
}

// one block per bucket: per-node histogram -> dinv + rowptr/rend, scatter col.
static __device__ __forceinline__ void finish_body(int b, const unsigned* __restrict__ ebuf,
                                                   const int* __restrict__ cnt, int cap, int n,
                                                   int* __restrict__ rowptr,
                                                   int* __restrict__ rend,
                                                   float* __restrict__ dinv,
                                                   int* __restrict__ col) {
    __shared__ int hist[BW];
    __shared__ int cur[BW];
    __shared__ int sh[256];
    const int t = threadIdx.x;
    const int nb = b << BSH;
    const int w = min(BW, n - nb);
    const int rb = b * cap;
    const int re = rb + cnt[b];
    hist[2 * t] = 0; hist[2 * t + 1] = 0;
    __syncthreads();
    for (int i = rb + t; i < re; i += 256) atomicAdd(&hist[ebuf[i] & (BW - 1)], 1);
    __syncthreads();
    const int a0 = hist[2 * t], a1 = hist[2 * t + 1];
    if (2 * t     < w) dinv[nb + 2 * t]     = rsqrtf((float)(a0 + 1));
    if (2 * t + 1 < w) dinv[nb + 2 * t + 1] = rsqrtf((float)(a1 + 1));
    sh[t] = a0 + a1; __syncthreads();
    for (int off = 1; off < 256; off <<= 1) {
        int add = (t >= off) ? sh[t - off] : 0;
        __syncthreads(); sh[t] += add; __syncthreads();
    }
    int base = t ? sh[t - 1] : 0;
    const int p0 = rb + base, p1 = rb + base + a0;
    if (2 * t < w) {
        rowptr[nb + 2 * t] = p0;
        rend[nb + 2 * t]   = p1;
    }
    if (2 * t + 1 < w) {
        rowptr[nb + 2 * t + 1] = p1;
        rend[nb + 2 * t + 1]   = p1 + a1;
    }
    cur[2 * t] = p0; cur[2 * t + 1] = p1;
    __syncthreads();
    for (int i = rb + t; i < re; i += 256) {
        unsigned r = ebuf[i];
        int pos = atomicAdd(&cur[r & (BW - 1)], 1);
        col[pos] = (int)(r >> BSH);
    }
}

__global__ __launch_bounds__(256) void csr_finish2(const unsigned* ebp, const int* gcp, int capp,
                                                   int np_, int* rpp, int* rep, float* dvp,
                                                   int* clp, int nbkp,
                                                   const unsigned* ebd, const int* gcd, int capd,
                                                   int nd_, int* rpd, int* red, float* dvd,
                                                   int* cld) {
    int b = blockIdx.x;
    if (b < nbkp) finish_body(b, ebp, gcp, capp, np_, rpp, rep, dvp, clp);
    else          finish_body(b - nbkp, ebd, gcd, capd, nd_, rpd, red, dvd, cld);
}

// ---- x@W via MFMA f16; out = fp8( dinv[row] * (x@W) ), rows 128B ------------
template <int K, bool IN16>
static __device__ __forceinline__ void xw_body(_Float16* __restrict__ Wt,
                                               unsigned char* __restrict__ T8, int bid,
                                               const void* __restrict__ xv,
                                               const float* __restrict__ W,
                                               const float* __restrict__ dinv,
                                               uint4* __restrict__ out8, int n) {
    constexpr int CH = K / 8;
    constexpr int KS = K / 32;
    const int tid = threadIdx.x;

    for (int i = tid; i < 128 * CH; i += 256) {
        const int col = i / CH, ch = i % CH;
        f16x8 v;
        #pragma unroll
        for (int j = 0; j < 8; ++j) v[j] = (_Float16)W[(ch * 8 + j) * 128 + col];
        *(f16x8*)&Wt[(col * CH + (ch ^ (col & (CH - 1)))) * 8] = v;
    }
    __syncthreads();

    const int wv = tid >> 6, ln = tid & 63;
    const int r0 = bid * 64 + wv * 16;
    const int row = r0 + (ln & 15);
    const int kg = (ln >> 4) * 8;

    f16x8 a[KS];
    if (row < n) {
        if constexpr (IN16) {
            const unsigned short* xr = (const unsigned short*)xv + (size_t)row * K;
            #pragma unroll
            for (int ks = 0; ks < KS; ++ks)
                a[ks] = *(const f16x8*)&xr[ks * 32 + kg];
        } else {
            const float* xr = (const float*)xv + (size_t)row * K;
            #pragma unroll
            for (int ks = 0; ks < KS; ++ks) {
                float4 u0 = *(const float4*)&xr[ks * 32 + kg];
                float4 u1 = *(const float4*)&xr[ks * 32 + kg + 4];
                f16x8 v;
                v[0] = (_Float16)u0.x; v[1] = (_Float16)u0.y;
                v[2] = (_Float16)u0.z; v[3] = (_Float16)u0.w;
                v[4] = (_Float16)u1.x; v[5] = (_Float16)u1.y;
                v[6] = (_Float16)u1.z; v[7] = (_Float16)u1.w;
                a[ks] = v;
            }
        }
    } else {
        #pragma unroll
        for (int ks = 0; ks < KS; ++ks) {
            f16x8 v;
            #pragma unroll
            for (int j = 0; j < 8; ++j) v[j] = (_Float16)0.f;
            a[ks] = v;
        }
    }

    const int rw0l = wv * 16 + (ln >> 4) * 4;   // local row of lane's 4 outputs
    float dv[4];
    #pragma unroll
    for (int r = 0; r < 4; ++r) dv[r] = (bid * 64 + rw0l + r < n) ? dinv[bid * 64 + rw0l + r] : 0.f;

    const int cl = ln & 15;
    #pragma unroll
    for (int nt = 0; nt < 8; ++nt) {
        const int col = nt * 16 + cl;
        f32x4 c = {0.f, 0.f, 0.f, 0.f};
        #pragma unroll
        for (int ks = 0; ks < KS; ++ks) {
            const int ch = ks * 4 + (ln >> 4);
            f16x8 b = *(const f16x8*)&Wt[(col * CH + (ch ^ (col & (CH - 1)))) * 8];
            c = __builtin_amdgcn_mfma_f32_16x16x32_f16(a[ks], b, c, 0, 0, 0);
        }
        #pragma unroll
        for (int r = 0; r < 4; ++r) {
            int q = __builtin_amdgcn_cvt_pk_fp8_f32(c[r] * dv[r], 0.f, 0, false);
            T8[(rw0l + r) * 128 + col] = (unsigned char)q;
        }
    }
    __syncthreads();
    // bulk store: 64 rows x 128B = 512 uint4
    for (int i = tid; i < 512; i += 256) {
        const int lr = i >> 3, ch = i & 7;
        const int rr = bid * 64 + lr;
        if (rr < n) out8[(size_t)rr * 8 + ch] = *(const uint4*)&T8[lr * 128 + ch * 16];
    }
    __syncthreads();
}

__global__ __launch_bounds__(256) void xw1_fused(const float* xp, const float* Wp,
                                                 const float* dvp, uint4* op, int np_, int nbp,
                                                 const float* xd, const float* Wd,
                                                 const float* dvd, uint4* od, int nd_) {
    __shared__ _Float16 Wt[128 * 128];
    __shared__ unsigned char T8[64 * 128];
    int b = blockIdx.x;
    if (b < nbp) xw_body<128, false>(Wt, T8, b, xp, Wp, dvp, op, np_);
    else         xw_body<64,  false>(Wt, T8, b - nbp, xd, Wd, dvd, od, nd_);
}

__global__ __launch_bounds__(256) void xw2_fused(const unsigned short* xp, const float* Wp,
                                                 const float* dvp, uint4* op, int np_, int nbp,
                                                 const unsigned short* xd, const float* Wd,
                                                 const float* dvd, uint4* od, int nd_) {
    __shared__ _Float16 Wt[128 * 128];
    __shared__ unsigned char T8[64 * 128];
    int b = blockIdx.x;
    if (b < nbp) xw_body<128, true>(Wt, T8, b, xp, Wp, dvp, op, np_);
    else         xw_body<128, true>(Wt, T8, b - nbp, xd, Wd, dvd, od, nd_);
}

// ---- aggregation: R12 structure, 32-bit byte-offset gathers -----------------
// tab row = 128B fp8. lane = (group g = ln>>4, chunk c = ln&15). Addresses:
// SGPR base (tab) + 32-bit VGPR offset (s<<7 | c<<3) — tables <= 12.8MB.
static __device__ __forceinline__ void agg_body(int bid, const char* __restrict__ tab,
                                                const int* __restrict__ rowptr,
                                                const int* __restrict__ rend,
                                                const float* __restrict__ dinv,
                                                const int* __restrict__ col,
                                                const float* __restrict__ bias,
                                                uint4* __restrict__ out, int n) {
    const int wv = threadIdx.x >> 6, ln = threadIdx.x & 63;
    const int d = bid * 4 + wv;
    if (d >= n) return;
    const int g = ln >> 4;
    const unsigned coff = (unsigned)(ln & 15) << 3;   // byte offset of chunk in row
    const int c = ln & 15;
    const int beg = rowptr[d], end = rend[d];

    f32x2 a[4], b[4];
    #pragma unroll
    for (int i = 0; i < 4; ++i) { a[i] = (f32x2){0.f, 0.f}; b[i] = (f32x2){0.f, 0.f}; }
    if (g == 0) {                       // self-loop term
        uint2 v = *(const uint2*)(tab + (((unsigned)d << 7) + coff));
        acc8v(a, v.x, v.y);
    }

    int j = beg;
    unsigned o0 = 0, o1 = 0;
    if (j + 8 <= end) {
        o0 = ((unsigned)col[j + g] << 7) + coff;
        o1 = ((unsigned)col[j + 4 + g] << 7) + coff;
    }
    for (; j + 16 <= end; j += 8) {     // prefetch next offsets while gathers fly
        uint2 v0 = *(const uint2*)(tab + o0);
        uint2 v1 = *(const uint2*)(tab + o1);
        o0 = ((unsigned)col[j + 8 + g] << 7) + coff;
        o1 = ((unsigned)col[j + 12 + g] << 7) + coff;
        acc8v(a, v0.x, v0.y);
        acc8v(b, v1.x, v1.y);
    }
    if (j + 8 <= end) {                 // consume the last prefetched pair
        uint2 v0 = *(const uint2*)(tab + o0);
        uint2 v1 = *(const uint2*)(tab + o1);
        acc8v(a, v0.x, v0.y);
        acc8v(b, v1.x, v1.y);
        j += 8;
    }
    for (; j < end; j += 4) {           // tail quads (predicated)
        int jj = j + g;
        unsigned o = ((unsigned)col[min(jj, end - 1)] << 7) + coff;
        uint2 v = *(const uint2*)(tab + o);
        if (jj < end) acc8v(b, v.x, v.y);
    }
    #pragma unroll
    for (int i = 0; i < 4; ++i) a[i] += b[i];

    float r[8];
    #pragma unroll
    for (int i = 0; i < 4; ++i) { r[2 * i] = a[i][0]; r[2 * i + 1] = a[i][1]; }
    #pragma unroll
    for (int i = 0; i < 8; ++i) r[i] += __shfl_xor(r[i], 16);
    #pragma unroll
    for (int i = 0; i < 8; ++i) r[i] += __shfl_xor(r[i], 32);

    if (g == 0) {
        const float dv = dinv[d];
        const float* bp = &bias[c * 8];
        uint4 o;
        o.x = (unsigned)f2h(fmaxf(fmaf(dv, r[0], bp[0]), 0.f))
            | ((unsigned)f2h(fmaxf(fmaf(dv, r[1], bp[1]), 0.f)) << 16);
        o.y = (unsigned)f2h(fmaxf(fmaf(dv, r[2], bp[2]), 0.f))
            | ((unsigned)f2h(fmaxf(fmaf(dv, r[3], bp[3]), 0.f)) << 16);
        o.z = (unsigned)f2h(fmaxf(fmaf(dv, r[4], bp[4]), 0.f))
            | ((unsigned)f2h(fmaxf(fmaf(dv, r[5], bp[5]), 0.f)) << 16);
        o.w = (unsigned)f2h(fmaxf(fmaf(dv, r[6], bp[6]), 0.f))
            | ((unsigned)f2h(fmaxf(fmaf(dv, r[7], bp[7]), 0.f)) << 16);
        out[(size_t)d * 16 + c] = o;
    }
}

__global__ __launch_bounds__(256) void agg_fused(const char* tp, const int* rpp, const int* rep,
                                                 const float* dvp, const int* clp, const float* bp,
                                                 uint4* op, int np_, int nwbp,
                                                 const char* td, const int* rpd, const int* red,
                                                 const float* dvd, const int* cld, const float* bd,
                                                 uint4* od, int nd_) {
    int b = blockIdx.x;
    if (b < nwbp) agg_body(b, tp, rpp, rep, dvp, clp, bp, op, np_);
    else          agg_body(b - nwbp, td, rpd, red, dvd, cld, bd, od, nd_);
}

// ---- mean over rows (f16 input) + seq MLP l1, merged ------------------------
static __device__ __forceinline__ void meanp_body(int bid, const uint4* __restrict__ h, int n,
                                                  int nblk, float* __restrict__ partial) {
    const int t = threadIdx.x;
    const int c = t & 15;
    const int rl = t >> 4;
    const int rpb = (n + nblk - 1) / nblk;
    const int r0 = bid * rpb, r1 = min(n, r0 + rpb);
    float acc[8] = {0.f, 0.f, 0.f, 0.f, 0.f, 0.f, 0.f, 0.f};
    for (int r = r0 + rl; r < r1; r += 16) {
        uint4 v = h[(size_t)r * 16 + c];
        f16x2 p;
        p = u2h(v.x); acc[0] += (float)p[0]; acc[1] += (float)p[1];
        p = u2h(v.y); acc[2] += (float)p[0]; acc[3] += (float)p[1];
        p = u2h(v.z); acc[4] += (float)p[0]; acc[5] += (float)p[1];
        p = u2h(v.w); acc[6] += (float)p[0]; acc[7] += (float)p[1];
    }
    __shared__ float sh[16][128];
    #pragma unroll
    for (int k = 0; k < 8; ++k) sh[rl][c * 8 + k] = acc[k];
    __syncthreads();
    if (t < 128) {
        float s = 0.f;
        #pragma unroll
        for (int i = 0; i < 16; ++i) s += sh[i][t];
        partial[(size_t)bid * 128 + t] = s;
    }
}

static __device__ __forceinline__ void l1_body(int bid, const float* __restrict__ in,
                                               const float* __restrict__ w1, int IN,
                                               float* __restrict__ partial) {
    const int t = threadIdx.x;
    const int f = t & 127;
    const int half = t >> 7;
    const int kpb = IN / MLP_NB;
    const int k0 = bid * kpb;
    float acc = 0.f;
    #pragma unroll 4
    for (int k = k0 + half; k < k0 + kpb; k += 2)
        acc = fmaf(in[k], w1[(size_t)k * 128 + f], acc);
    __shared__ float sh2[256];
    sh2[t] = acc; __syncthreads();
    if (half == 0) partial[bid * 128 + f] = sh2[f] + sh2[128 + f];
}

__global__ __launch_bounds__(256) void meansq_fused(const uint4* hp, int np_, float* pp,
                                                    const uint4* hd, int nd_, float* pd,
                                                    const float* inp, const float* w1p, int INp,
                                                    float* mp,
                                                    const float* ind, const float* w1d, int INd,
                                                    float* md) {
    int b = blockIdx.x;
    if      (b < MPP)                 meanp_body(b, hp, np_, MPP, pp);
    else if (b < MPP + MPD)           meanp_body(b - MPP, hd, nd_, MPD, pd);
    else if (b < MPP + MPD + MLP_NB)  l1_body(b - MPP - MPD, inp, w1p, INp, mp);
    else                              l1_body(b - MPP - MPD - MLP_NB, ind, w1d, INd, md);
}

// ---- mean finish + seq finish -----------------------------------------------
static __device__ __forceinline__ void meanf_body(const float* __restrict__ partial, int nrows,
                                                  float inv_n, float* __restrict__ out) {
    const int t = threadIdx.x;
    const int c4 = (t & 31) * 4;
    float4 acc = make_float4(0.f, 0.f, 0.f, 0.f);
    for (int r = (t >> 5); r < nrows; r += 8) {
        float4 v = *(const float4*)&partial[(size_t)r * 128 + c4];
        acc.x += v.x; acc.y += v.y; acc.z += v.z; acc.w += v.w;
    }
    __shared__ float4 sh[256];
    sh[t] = acc; __syncthreads();
    for (int off = 128; off >= 32; off >>= 1) {
        if (t < off) {
            float4 a = sh[t], o = sh[t + off];
            a.x += o.x; a.y += o.y; a.z += o.z; a.w += o.w;
            sh[t] = a;
        }
        __syncthreads();
    }
    if (t < 32) {
        float4 a = sh[t];
        a.x *= inv_n; a.y *= inv_n; a.z *= inv_n; a.w *= inv_n;
        *(float4*)&out[c4] = a;
    }
}

static __device__ __forceinline__ void seqfin_body(const float* __restrict__ partial,
                                                   const float* __restrict__ b1,
                                                   const float* __restrict__ w2,
                                                   const float* __restrict__ b2,
                                                   float* __restrict__ out) {
    const int t = threadIdx.x;          // 256; only t<128 active around syncs
    __shared__ float h[128];
    if (t < 128) {
        float s = 0.f;
        #pragma unroll 8
        for (int i = 0; i < MLP_NB; ++i) s += partial[i * 128 + t];
        h[t] = fmaxf(s + b1[t], 0.f);
    }
    __syncthreads();
    if (t < 128) {
        float acc = 0.f;
        #pragma unroll 8
        for (int k = 0; k < 128; ++k) acc = fmaf(h[k], w2[k * 128 + t], acc);
        out[t] = fmaxf(acc + b2[t], 0.f);
    }
}

__global__ __launch_bounds__(256) void finish_fused(const float* pp, float invp, float* omp,
                                                    const float* pd, float invd, float* omd,
                                                    const float* sp, const float* b1p,
                                                    const float* w2p, const float* b2p, float* osp,
                                                    const float* sd, const float* b1d,
                                                    const float* w2d, const float* b2d, float* osd) {
    const int b = blockIdx.x;
    if      (b == 0) meanf_body(pp, MPP, invp, omp);
    else if (b == 1) meanf_body(pd, MPD, invd, omd);
    else if (b == 2) seqfin_body(sp, b1p, w2p, b2p, osp);
    else             seqfin_body(sd, b1d, w2d, b2d, osd);
}

// ---- head: one block, both layers -------------------------------------------
__global__ __launch_bounds__(256) void head_one(const float* pm, const float* dm,
                                                const float* ps, const float* ds2,
                                                const float* fc1w, const float* fc1b,
                                                const float* fc2w, const float* fc2b,
                                                float* out) {
    const int t = threadIdx.x;          // 256
    __shared__ float comb[512];
    if (t < 128) {
        comb[t] = pm[t]; comb[128 + t] = dm[t];
        comb[256 + t] = ps[t]; comb[384 + t] = ds2[t];
    }
    __syncthreads();
    const int f = t & 127, half = t >> 7;
    float acc = 0.f;
    const int kb = half * 256;
    #pragma unroll 8
    for (int k = kb; k < kb + 256; ++k)
        acc = fmaf(comb[k], fc1w[(size_t)k * 128 + f], acc);
    __shared__ float hs[256];
    hs[t] = acc; __syncthreads();
    __shared__ float red[128];
    if (t < 128) {
        float h = fmaxf(hs[t] + hs[128 + t] + fc1b[t], 0.f);
        red[t] = h * fc2w[t];
    }
    __syncthreads();
    for (int off = 64; off > 0; off >>= 1) {
        if (t < off) red[t] += red[t + off];
        __syncthreads();
    }
    if (t == 0) out[0] = red[0] + fc2b[0];
}

static inline size_t align_up(size_t x, size_t a) { return (x + a - 1) / a * a; }

extern "C" void kernel_launch(void* const* d_in, const int* in_sizes, int n_in,
                              void* d_out, int out_size, void* d_ws, size_t ws_size,
                              hipStream_t stream) {
    const float* px   = (const float*)d_in[0];
    const int*   pei  = (const int*)d_in[1];
    const float* dx   = (const float*)d_in[2];
    const int*   dei  = (const int*)d_in[3];
    const float* pseq = (const float*)d_in[4];
    const float* dseq = (const float*)d_in[5];
    const float* pc1w = (const float*)d_in[6];  const float* pc1b = (const float*)d_in[7];
    const float* pc2w = (const float*)d_in[8];  const float* pc2b = (const float*)d_in[9];
    const float* dc1w = (const float*)d_in[10]; const float* dc1b = (const float*)d_in[11];
    const float* dc2w = (const float*)d_in[12]; const float* dc2b = (const float*)d_in[13];
    const float* psw1 = (const float*)d_in[14]; const float* psb1 = (const float*)d_in[15];
    const float* psw2 = (const float*)d_in[16]; const float* psb2 = (const float*)d_in[17];
    const float* dsw1 = (const float*)d_in[18]; const float* dsb1 = (const float*)d_in[19];
    const float* dsw2 = (const float*)d_in[20]; const float* dsb2 = (const float*)d_in[21];
    const float* fc1w = (const float*)d_in[22]; const float* fc1b = (const float*)d_in[23];
    const float* fc2w = (const float*)d_in[24]; const float* fc2b = (const float*)d_in[25];

    const int Np = in_sizes[0] / 128, Ep = in_sizes[1] / 2;
    const int Nd = in_sizes[2] / 64,  Ed = in_sizes[3] / 2;
    const int Psd = in_sizes[4], Dsd = in_sizes[5];

    // bucket capacities (binomial mean E/256, std ~sqrt(E/256); huge slack)
    const int capP = (Ep / 256 + Ep / 2048 + 1024 + 63) & ~63;
    const int capD = (Ed / 256 + Ed / 2048 + 1024 + 63) & ~63;

    char* w = (char*)d_ws;
    size_t off = 0;
    auto carve = [&](size_t bytes) -> void* {
        void* p = w + off;
        off = align_up(off + bytes, 256);
        return p;
    };
    unsigned char* tab_p  = (unsigned char*)carve((size_t)Np * 128);      // fp8 msg table
    unsigned short* buf_p = (unsigned short*)carve((size_t)Np * 128 * 2); // f16 hidden
    unsigned char* tab_d  = (unsigned char*)carve((size_t)Nd * 128);
    unsigned short* buf_d = (unsigned short*)carve((size_t)Nd * 128 * 2);
    int*      col_p  = (int*)carve((size_t)256 * capP * 4);
    unsigned* ebuf_p = (unsigned*)carve((size_t)256 * capP * 4);
    int*      col_d  = (int*)carve((size_t)256 * capD * 4);
    unsigned* ebuf_d = (unsigned*)carve((size_t)256 * capD * 4);
    int*   gcur_p   = (int*)carve(256 * 4);
    int*   gcur_d   = (int*)carve(256 * 4);
    int*   rowptr_p = (int*)carve((size_t)Np * 4);
    int*   rend_p   = (int*)carve((size_t)Np * 4);
    int*   rowptr_d = (int*)carve((size_t)Nd * 4);
    int*   rend_d   = (int*)carve((size_t)Nd * 4);
    float* dinv_p   = (float*)carve((size_t)Np * 4);
    float* dinv_d   = (float*)carve((size_t)Nd * 4);
    float* part_p   = (float*)carve((size_t)MPP * 128 * 4);
    float* part_d   = (float*)carve((size_t)MPD * 128 * 4);
    float* mlpp_p   = (float*)carve((size_t)MLP_NB * 128 * 4);
    float* mlpp_d   = (float*)carve((size_t)MLP_NB * 128 * 4);
    float* pmean    = (float*)carve(512);
    float* dmean    = (float*)carve(512);
    float* pseqo    = (float*)carve(512);
    float* dseqo    = (float*)carve(512);
    (void)ws_size; (void)n_in; (void)out_size;

    const int* psrc = pei; const int* pdst = pei + Ep;
    const int* dsrc = dei; const int* ddst = dei + Ed;
    const int chp = (((Ep + NCB - 1) / NCB) + 255) & ~255;
    const int chd = (((Ed + NCB - 1) / NCB) + 255) & ~255;
    const int nbkp = (Np + BW - 1) >> BSH, nbkd = (Nd + BW - 1) >> BSH;
    const int nbp = (Np + 63) / 64, nbd = (Nd + 63) / 64;
    const int nwbp = (Np + 3) / 4, nwbd = (Nd + 3) / 4;

    // CSR build (hist+reserve+place fused; gcur_p/gcur_d adjacent -> one memset)
    hipMemsetAsync(gcur_p, 0, 512 * 4, stream);
    csr_build2<<<2 * NCB, 256, 0, stream>>>(psrc, pdst, Ep, chp, gcur_p, ebuf_p, capP,
                                            dsrc, ddst, Ed, chd, gcur_d, ebuf_d, capD);
    csr_finish2<<<nbkp + nbkd, 256, 0, stream>>>(ebuf_p, gcur_p, capP, Np, rowptr_p, rend_p,
                                                 dinv_p, col_p, nbkp,
                                                 ebuf_d, gcur_d, capD, Nd, rowptr_d, rend_d,
                                                 dinv_d, col_d);

    // conv1
    xw1_fused<<<nbp + nbd, 256, 0, stream>>>(px, pc1w, dinv_p, (uint4*)tab_p, Np, nbp,
                                             dx, dc1w, dinv_d, (uint4*)tab_d, Nd);
    agg_fused<<<nwbp + nwbd, 256, 0, stream>>>((const char*)tab_p, rowptr_p, rend_p, dinv_p,
                                               col_p, pc1b, (uint4*)buf_p, Np, nwbp,
                                               (const char*)tab_d, rowptr_d, rend_d, dinv_d,
                                               col_d, dc1b, (uint4*)buf_d, Nd);
    // conv2
    xw2_fused<<<nbp + nbd, 256, 0, stream>>>(buf_p, pc2w, dinv_p, (uint4*)tab_p, Np, nbp,
                                             buf_d, dc2w, dinv_d, (uint4*)tab_d, Nd);
    agg_fused<<<nwbp + nwbd, 256, 0, stream>>>((const char*)tab_p, rowptr_p, rend_p, dinv_p,
                                               col_p, pc2b, (uint4*)buf_p, Np, nwbp,
                                               (const char*)tab_d, rowptr_d, rend_d, dinv_d,
                                               col_d, dc2b, (uint4*)buf_d, Nd);
    // means + seq MLP layer 1 (one dispatch)
    meansq_fused<<<MPP + MPD + 2 * MLP_NB, 256, 0, stream>>>(
        (const uint4*)buf_p, Np, part_p, (const uint4*)buf_d, Nd, part_d,
        pseq, psw1, Psd, mlpp_p, dseq, dsw1, Dsd, mlpp_d);
    // mean finish + seq finish (one dispatch)
    finish_fused<<<4, 256, 0, stream>>>(part_p, 1.0f / (float)Np, pmean,
                                        part_d, 1.0f / (float)Nd, dmean,
                                        mlpp_p, psb1, psw2, psb2, pseqo,
                                        mlpp_d, dsb1, dsw2, dsb2, dseqo);
    // head (single block, both layers)
    head_one<<<1, 256, 0, stream>>>(pmean, dmean, pseqo, dseqo, fc1w, fc1b, fc2w, fc2b,
                                    (float*)d_out);
}